// Round 5
// baseline (11796.033 us; speedup 1.0000x reference)
//
#include <hip/hip_runtime.h>
#include <math.h>

#define T_STEPS 64
#define BATCH   32
#define SEQ     64
#define HID     512
#define VOCAB   32000
#define ABASE   16000   // outs (A-matrix) band: f32 cols [16000,16512) of each logits row
#define SBASE   16512   // fp32 state band: f32 cols [16512,16576) of logits rows [0,1536)

typedef unsigned short u16;
typedef unsigned int   u32;

typedef __attribute__((ext_vector_type(8))) short short8;
typedef __attribute__((ext_vector_type(4))) float f32x4;

__device__ __forceinline__ u16 f2bf(float f) {
  u32 x = __float_as_uint(f);
  u32 r = (x + 0x7fffu + ((x >> 16) & 1u)) >> 16;
  return (u16)r;
}
__device__ __forceinline__ float sigf(float x) { return 1.0f / (1.0f + expf(-x)); }

// fp32 state element i lives at logits row (i>>6), f32 col SBASE + (i&63).
// 64 floats per row; float4 access valid when i % 4 == 0 (never crosses a row).
__device__ __forceinline__ float* stP(float* o, int i) {
  return o + (size_t)(i >> 6) * VOCAB + SBASE + (i & 63);
}
// state index map: h: buf*32768 + layer*16384 + b*512 + u  (buf in {0,1})
//                  c: 65536 + layer*16384 + b*512 + u

// ---------------------------------------------------------------------------
__global__ __launch_bounds__(256) void init_kernel(
    const float* __restrict__ h0, const float* __restrict__ c0, float* o)
{
  int idx = blockIdx.x * 256 + threadIdx.x;
  if (idx < 32768) {
    *stP(o, idx)         = h0[idx];   // buf0, both layers
    *stP(o, 65536 + idx) = c0[idx];   // c, both layers
  }
}

// ---------------------------------------------------------------------------
// LSTM: one block = 2 hidden units (4 gates x 32 batch rows)
// ---------------------------------------------------------------------------
__device__ __forceinline__ void lstm_tail(
    float* o, float acc, int up, float* gl, int hout_base, int c_base)
{
  const int tid = threadIdx.x;
  gl[tid] = acc;                 // tid == g*32+b
  __syncthreads();
  if (tid < 64) {
    int b2 = tid & 31, du2 = tid >> 5;
    int u2 = up * 2 + du2;
    float iv = sigf(gl[(0 * 2 + du2) * 32 + b2]);
    float fv = sigf(gl[(1 * 2 + du2) * 32 + b2]);
    float gv = tanhf(gl[(2 * 2 + du2) * 32 + b2]);
    float ov = sigf(gl[(3 * 2 + du2) * 32 + b2]);
    float* cp = stP(o, c_base + b2 * HID + u2);
    float cn = fv * (*cp) + iv * gv;
    *cp = cn;
    *stP(o, hout_base + b2 * HID + u2) = ov * tanhf(cn);
  }
}

// layer0: x row = embedding[tokens[b,t]] (f32)
__device__ __forceinline__ void lstm_l0_block(
    float* o, const int* __restrict__ tokens, const float* __restrict__ emb, int t,
    int hin_base, int hout_base, int c_base,
    const float* __restrict__ Wih, const float* __restrict__ Whh,
    const float* __restrict__ bih, const float* __restrict__ bhh,
    int up, float* gl)
{
  const int tid = threadIdx.x;
  const int b = tid & 31, g = tid >> 5, q = g >> 1, du = g & 1;
  const int u = up * 2 + du, j = q * HID + u;
  const float4* xb = (const float4*)(emb + (size_t)tokens[b * T_STEPS + t] * HID);
  const float4* wi = (const float4*)(Wih + (size_t)j * HID);
  const float4* wh = (const float4*)(Whh + (size_t)j * HID);
  const int hb0 = hin_base + b * HID;
  float acc = 0.f;
#pragma unroll 4
  for (int k = 0; k < HID / 4; ++k) {
    float4 xv = xb[k]; float4 wv = wi[k];
    acc += wv.x * xv.x + wv.y * xv.y + wv.z * xv.z + wv.w * xv.w;
    float4 hv = *(const float4*)stP(o, hb0 + 4 * k); float4 wv2 = wh[k];
    acc += wv2.x * hv.x + wv2.y * hv.y + wv2.z * hv.z + wv2.w * hv.w;
  }
  acc += bih[j] + bhh[j];
  lstm_tail(o, acc, up, gl, hout_base, c_base);
}

// layer1: x = fp32 h of layer0 (state band)
__device__ __forceinline__ void lstm_l1_block(
    float* o, int x_base, int hin_base, int hout_base, int c_base,
    const float* __restrict__ Wih, const float* __restrict__ Whh,
    const float* __restrict__ bih, const float* __restrict__ bhh,
    int up, float* gl)
{
  const int tid = threadIdx.x;
  const int b = tid & 31, g = tid >> 5, q = g >> 1, du = g & 1;
  const int u = up * 2 + du, j = q * HID + u;
  const float4* wi = (const float4*)(Wih + (size_t)j * HID);
  const float4* wh = (const float4*)(Whh + (size_t)j * HID);
  const int xb0 = x_base + b * HID;
  const int hb0 = hin_base + b * HID;
  float acc = 0.f;
#pragma unroll 4
  for (int k = 0; k < HID / 4; ++k) {
    float4 xv = *(const float4*)stP(o, xb0 + 4 * k); float4 wv = wi[k];
    acc += wv.x * xv.x + wv.y * xv.y + wv.z * xv.z + wv.w * xv.w;
    float4 hv = *(const float4*)stP(o, hb0 + 4 * k); float4 wv2 = wh[k];
    acc += wv2.x * hv.x + wv2.y * hv.y + wv2.z * hv.z + wv2.w * hv.w;
  }
  acc += bih[j] + bhh[j];
  lstm_tail(o, acc, up, gl, hout_base, c_base);
}

__global__ __launch_bounds__(256) void lstm0_kernel(
    float* o, const int* __restrict__ tokens, const float* __restrict__ emb, int t,
    int hin_base, int hout_base, int c_base,
    const float* __restrict__ Wih, const float* __restrict__ Whh,
    const float* __restrict__ bih, const float* __restrict__ bhh)
{
  __shared__ float gl[256];
  lstm_l0_block(o, tokens, emb, t, hin_base, hout_base, c_base,
                Wih, Whh, bih, bhh, blockIdx.x, gl);
}

__global__ __launch_bounds__(256) void lstm1_kernel(
    float* o, int x_base, int hin_base, int hout_base, int c_base,
    const float* __restrict__ Wih, const float* __restrict__ Whh,
    const float* __restrict__ bih, const float* __restrict__ bhh)
{
  __shared__ float gl[256];
  lstm_l1_block(o, x_base, hin_base, hout_base, c_base,
                Wih, Whh, bih, bhh, blockIdx.x, gl);
}

// ---------------------------------------------------------------------------
// fused: blocks [0,32) = attention(t) for batch b; blocks [32,288) = L0(t+1)
// ---------------------------------------------------------------------------
__global__ __launch_bounds__(256) void attn_l0_kernel(
    float* o, const float* __restrict__ context,
    const float* __restrict__ Wai, const float* __restrict__ Wao,
    float* __restrict__ o_attn, int t, int do_l0, int h1_base,
    const int* __restrict__ tokens, const float* __restrict__ emb,
    int hin0_base, int hout0_base, int c0_base,
    const float* __restrict__ Wih0, const float* __restrict__ Whh0,
    const float* __restrict__ bih0, const float* __restrict__ bhh0)
{
  if (blockIdx.x >= 32) {
    if (!do_l0) return;
    __shared__ float gl[256];
    lstm_l0_block(o, tokens, emb, t + 1, hin0_base, hout0_base, c0_base,
                  Wih0, Whh0, bih0, bhh0, blockIdx.x - 32, gl);
    return;
  }
  const int b = blockIdx.x;
  const int tid = threadIdx.x;
  __shared__ float hb[HID], qv[HID], cx[HID], sc[SEQ], at[SEQ];
  hb[tid]       = *stP(o, h1_base + b * HID + tid);
  hb[tid + 256] = *stP(o, h1_base + b * HID + tid + 256);
  __syncthreads();
  // q = h1 @ W_attn_in^T
#pragma unroll
  for (int jj = 0; jj < 2; ++jj) {
    int j = tid + jj * 256;
    const float4* w = (const float4*)(Wai + (size_t)j * HID);
    float acc = 0.f;
    for (int k = 0; k < HID / 4; ++k) {
      float4 wv = w[k];
      acc += wv.x * hb[4 * k] + wv.y * hb[4 * k + 1]
           + wv.z * hb[4 * k + 2] + wv.w * hb[4 * k + 3];
    }
    qv[j] = acc;
  }
  __syncthreads();
  if (tid < SEQ) {
    const float4* cp = (const float4*)(context + ((size_t)b * SEQ + tid) * HID);
    float acc = 0.f;
    for (int k = 0; k < HID / 4; ++k) {
      float4 cv = cp[k];
      acc += cv.x * qv[4 * k] + cv.y * qv[4 * k + 1]
           + cv.z * qv[4 * k + 2] + cv.w * qv[4 * k + 3];
    }
    sc[tid] = acc;
  }
  __syncthreads();
  if (tid == 0) {
    float mx = -1e30f;
    for (int s = 0; s < SEQ; ++s) mx = fmaxf(mx, sc[s]);
    float sum = 0.f;
    for (int s = 0; s < SEQ; ++s) { float e = expf(sc[s] - mx); at[s] = e; sum += e; }
    float inv = 1.0f / sum;
    for (int s = 0; s < SEQ; ++s) at[s] *= inv;
  }
  __syncthreads();
  if (tid < SEQ) o_attn[b * SEQ + tid] = at[tid];
#pragma unroll
  for (int jj = 0; jj < 2; ++jj) {
    int h = tid + jj * 256;
    float acc = 0.f;
    for (int s = 0; s < SEQ; ++s)
      acc += at[s] * context[((size_t)b * SEQ + s) * HID + h];
    cx[h] = acc;
  }
  __syncthreads();
#pragma unroll
  for (int jj = 0; jj < 2; ++jj) {
    int j = tid + jj * 256;
    const float4* w1 = (const float4*)(Wao + (size_t)j * 2 * HID);
    const float4* w2 = (const float4*)(Wao + (size_t)j * 2 * HID + HID);
    float acc = 0.f;
    for (int k = 0; k < HID / 4; ++k) {
      float4 wv = w1[k];
      acc += wv.x * cx[4 * k] + wv.y * cx[4 * k + 1]
           + wv.z * cx[4 * k + 2] + wv.w * cx[4 * k + 3];
    }
    for (int k = 0; k < HID / 4; ++k) {
      float4 wv = w2[k];
      acc += wv.x * hb[4 * k] + wv.y * hb[4 * k + 1]
           + wv.z * hb[4 * k + 2] + wv.w * hb[4 * k + 3];
    }
    // outs row (t*32+b), element j -> A-band home (f32)
    o[(size_t)(t * BATCH + b) * VOCAB + ABASE + j] = tanhf(acc);
  }
}

// ---------------------------------------------------------------------------
// vocab GEMM pass A: 490 col-tiles avoiding cols [16000,16640).
// A and B are f32 in memory; converted to bf16 while staging to LDS.
// ---------------------------------------------------------------------------
__device__ __forceinline__ short8 pack8(const float* p) {
  float4 a = *(const float4*)p, b = *(const float4*)(p + 4);
  short8 r;
  r[0] = (short)f2bf(a.x); r[1] = (short)f2bf(a.y);
  r[2] = (short)f2bf(a.z); r[3] = (short)f2bf(a.w);
  r[4] = (short)f2bf(b.x); r[5] = (short)f2bf(b.y);
  r[6] = (short)f2bf(b.z); r[7] = (short)f2bf(b.w);
  return r;
}

__global__ __launch_bounds__(256) void vocab_gemm_a(
    float* o, const float* __restrict__ Bw, const float* __restrict__ bias)
{
  __shared__ __align__(16) u16 As[4 * 64 * 8];
  __shared__ __align__(16) u16 Bs[4 * 64 * 8];
  const int tid = threadIdx.x;
  const int wv   = tid >> 6;
  const int lane = tid & 63;
  const int m16  = lane & 15;
  const int quad = lane >> 4;
  const int ct = (blockIdx.x < 250) ? blockIdx.x : blockIdx.x + 10;
  const int rowBase = blockIdx.y * 64;
  const int colBase = ct * 64;
  const int srow = tid >> 2;
  const int scg  = tid & 3;
  f32x4 acc[4];
#pragma unroll
  for (int nt = 0; nt < 4; ++nt)
#pragma unroll
    for (int r = 0; r < 4; ++r) acc[nt][r] = 0.f;

  for (int k0 = 0; k0 < HID; k0 += 32) {
    __syncthreads();
    *(short8*)&As[(scg * 64 + srow) * 8] =
        pack8(&o[(size_t)(rowBase + srow) * VOCAB + ABASE + k0 + scg * 8]);
    *(short8*)&Bs[(scg * 64 + srow) * 8] =
        pack8(&Bw[(size_t)(colBase + srow) * HID + k0 + scg * 8]);
    __syncthreads();
    short8 a = *(const short8*)&As[(quad * 64 + wv * 16 + m16) * 8];
#pragma unroll
    for (int nt = 0; nt < 4; ++nt) {
      short8 bfr = *(const short8*)&Bs[(quad * 64 + nt * 16 + m16) * 8];
      acc[nt] = __builtin_amdgcn_mfma_f32_16x16x32_bf16(a, bfr, acc[nt], 0, 0, 0);
    }
  }
#pragma unroll
  for (int nt = 0; nt < 4; ++nt) {
    int col = colBase + nt * 16 + m16;
    float bv = bias[col];
#pragma unroll
    for (int r = 0; r < 4; ++r) {
      int row = rowBase + wv * 16 + quad * 4 + r;
      o[(size_t)row * VOCAB + col] = acc[nt][r] + bv;
    }
  }
}

// ---------------------------------------------------------------------------
// pass B: the 10 band col-tiles. One block per 32-row tile; A staged to LDS
// BEFORE any write; writes are row-local -> no inter-block clobber.
// ---------------------------------------------------------------------------
__global__ __launch_bounds__(256) void vocab_gemm_b(
    float* o, const float* __restrict__ Bw, const float* __restrict__ bias)
{
  __shared__ __align__(16) u16 As[32 * 512];   // 32 KB bf16
  const int tid = threadIdx.x;
  const int rowBase = blockIdx.x * 32;
  for (int i = tid; i < 2048; i += 256) {      // 2048 chunks of 8
    int r = i >> 6, kk = (i & 63) * 8;
    *(short8*)&As[r * 512 + kk] =
        pack8(&o[(size_t)(rowBase + r) * VOCAB + ABASE + kk]);
  }
  __syncthreads();
  const int lane = tid & 63, w = tid >> 6;
  const int m16 = lane & 15, quad = lane >> 4;
  const int rg = w & 1, cg = w >> 1;
  for (int ctile = 250; ctile < 260; ++ctile) {
    int colBase = ctile * 64 + cg * 32;
    f32x4 acc[2];
#pragma unroll
    for (int nt = 0; nt < 2; ++nt)
#pragma unroll
      for (int r = 0; r < 4; ++r) acc[nt][r] = 0.f;
    for (int k0 = 0; k0 < HID; k0 += 32) {
      short8 a = *(const short8*)&As[(rg * 16 + m16) * 512 + k0 + quad * 8];
#pragma unroll
      for (int nt = 0; nt < 2; ++nt) {
        short8 bfr = pack8(&Bw[(size_t)(colBase + nt * 16 + m16) * HID + k0 + quad * 8]);
        acc[nt] = __builtin_amdgcn_mfma_f32_16x16x32_bf16(a, bfr, acc[nt], 0, 0, 0);
      }
    }
#pragma unroll
    for (int nt = 0; nt < 2; ++nt) {
      int col = colBase + nt * 16 + m16;
      float bv = bias[col];
#pragma unroll
      for (int r = 0; r < 4; ++r) {
        int row = rowBase + rg * 16 + quad * 4 + r;
        o[(size_t)row * VOCAB + col] = acc[nt][r] + bv;
      }
    }
  }
}

// ---------------------------------------------------------------------------
// log-softmax over V=32000, 3-pass global (rows are L2/L3-hot)
// ---------------------------------------------------------------------------
__global__ __launch_bounds__(256) void logsoftmax_kernel(float* logits)
{
  __shared__ float red[256];
  const int tid = threadIdx.x;
  float* rowp = logits + (size_t)blockIdx.x * VOCAB;
  float mx = -1e30f;
  for (int i = tid; i < VOCAB / 4; i += 256) {
    float4 v = ((const float4*)rowp)[i];
    mx = fmaxf(mx, fmaxf(fmaxf(v.x, v.y), fmaxf(v.z, v.w)));
  }
  red[tid] = mx; __syncthreads();
  for (int s = 128; s > 0; s >>= 1) {
    if (tid < s) red[tid] = fmaxf(red[tid], red[tid + s]);
    __syncthreads();
  }
  mx = red[0]; __syncthreads();
  float sum = 0.f;
  for (int i = tid; i < VOCAB / 4; i += 256) {
    float4 v = ((const float4*)rowp)[i];
    sum += expf(v.x - mx) + expf(v.y - mx) + expf(v.z - mx) + expf(v.w - mx);
  }
  red[tid] = sum; __syncthreads();
  for (int s = 128; s > 0; s >>= 1) {
    if (tid < s) red[tid] += red[tid + s];
    __syncthreads();
  }
  float lse = mx + logf(red[0]);
  for (int i = tid; i < VOCAB / 4; i += 256) {
    float4 v = ((const float4*)rowp)[i];
    float4 ov;
    ov.x = v.x - lse; ov.y = v.y - lse; ov.z = v.z - lse; ov.w = v.w - lse;
    ((float4*)rowp)[i] = ov;
  }
}

__global__ __launch_bounds__(256) void finalize_kernel(
    float* o, float* __restrict__ o_h, float* __restrict__ o_c)
{
  int idx = blockIdx.x * 256 + threadIdx.x;
  if (idx < 32768) {
    o_h[idx] = *stP(o, idx);           // final h = buf0
    o_c[idx] = *stP(o, 65536 + idx);
  }
}

// ---------------------------------------------------------------------------
extern "C" void kernel_launch(void* const* d_in, const int* in_sizes, int n_in,
                              void* d_out, int out_size, void* d_ws, size_t ws_size,
                              hipStream_t stream)
{
  (void)in_sizes; (void)n_in; (void)out_size; (void)d_ws; (void)ws_size;
  const int*   tokens  = (const int*)d_in[0];
  const float* h0      = (const float*)d_in[1];
  const float* c0      = (const float*)d_in[2];
  const float* context = (const float*)d_in[3];
  const float* emb     = (const float*)d_in[4];
  const float* Wih     = (const float*)d_in[5];
  const float* Whh     = (const float*)d_in[6];
  const float* bih     = (const float*)d_in[7];
  const float* bhh     = (const float*)d_in[8];
  const float* Wai     = (const float*)d_in[9];
  const float* Wao     = (const float*)d_in[10];
  const float* Wlin    = (const float*)d_in[11];
  const float* blin    = (const float*)d_in[12];

  float* o      = (float*)d_out;
  float* o_h    = o + (size_t)2048 * VOCAB;
  float* o_c    = o_h + 32768;
  float* o_attn = o_c + 32768;

  init_kernel<<<128, 256, 0, stream>>>(h0, c0, o);

  // L0, t=0: h buf0 -> buf1
  lstm0_kernel<<<256, 256, 0, stream>>>(o, tokens, emb, 0,
      /*hin*/0, /*hout*/32768, /*c*/65536, Wih, Whh, bih, bhh);
  for (int t = 0; t < T_STEPS; ++t) {
    const int cur = (t + 1) & 1;   // buf holding h0(t); receives h1(t)
    const int nxt = t & 1;         // buf holding h1(t-1); receives h0(t+1)
    lstm1_kernel<<<256, 256, 0, stream>>>(o,
        /*x   */ cur * 32768,
        /*hin */ nxt * 32768 + 16384,
        /*hout*/ cur * 32768 + 16384,
        /*c   */ 65536 + 16384,
        Wih + 1048576, Whh + 1048576, bih + 2048, bhh + 2048);
    const int do_l0 = (t + 1 < T_STEPS) ? 1 : 0;
    attn_l0_kernel<<<do_l0 ? 288 : 32, 256, 0, stream>>>(o, context, Wai, Wao,
        o_attn, t, do_l0,
        /*h1  */ cur * 32768 + 16384,
        tokens, emb,
        /*hin0*/ cur * 32768,
        /*hout0*/ nxt * 32768,
        /*c0  */ 65536,
        Wih, Whh, bih, bhh);
  }

  finalize_kernel<<<128, 256, 0, stream>>>(o, o_h, o_c);   // before pass B clobbers state band
  vocab_gemm_a<<<dim3(490, 32), 256, 0, stream>>>(o, Wlin, blin);
  vocab_gemm_b<<<64, 256, 0, stream>>>(o, Wlin, blin);
  logsoftmax_kernel<<<2048, 256, 0, stream>>>(o);
}